// Round 3
// baseline (261.554 us; speedup 1.0000x reference)
//
#include <hip/hip_runtime.h>
#include <hip/hip_bf16.h>

// Problem: B=8, T=256, V=32, D=256.
// Per-v GEMM: M=N=2048 (rows = i*T+q / j*T+k), K=256, then exp + 3 reductions.
// feature[B,T,V,D]: element (row, v, d) at feat[(row*32 + v)*256 + d].
// Packed bf16 keeps the SAME [row][v][d] layout (global_load_lds gathers
// per-lane on the global side; only the LDS side must be lane-contiguous).
// A-side is prescaled by log2(e) so the epilogue exp is a bare v_exp_f32.

typedef __attribute__((ext_vector_type(8))) __bf16 bf16x8;
typedef __attribute__((ext_vector_type(4))) float f32x4;

#if __has_builtin(__builtin_amdgcn_exp2f)
#define EXP2(x) __builtin_amdgcn_exp2f(x)
#else
#define EXP2(x) exp2f(x)
#endif

__device__ __forceinline__ unsigned short f2bf(float f) {
    unsigned u = __builtin_bit_cast(unsigned, f);
    u += 0x7FFFu + ((u >> 16) & 1u);   // RNE (no NaNs in data)
    return (unsigned short)(u >> 16);
}

__device__ __forceinline__ void async16(const unsigned short* g, unsigned short* l) {
    __builtin_amdgcn_global_load_lds(
        (const __attribute__((address_space(1))) unsigned int*)g,
        (__attribute__((address_space(3))) unsigned int*)l,
        16, 0, 0);
}

// ------------- repack: pure streaming fp32 -> bf16 (same layout) -------------
// grid (2048, 2): one row (8192 floats) per block; y selects tensor.
// A (feature) gets scaled by log2(e); B unscaled.
__global__ __launch_bounds__(256) void infonce_repack(
    const float* __restrict__ feat, const float* __restrict__ feat_aug,
    unsigned short* __restrict__ pA, unsigned short* __restrict__ pB)
{
    const int row = blockIdx.x;
    const int tid = threadIdx.x;
    const bool isA = (blockIdx.y == 0);
    const float scale = isA ? 1.4426950408889634f : 1.0f;
    const float* src = (isA ? feat : feat_aug) + (size_t)row * 8192;
    unsigned short* dst = (isA ? pA : pB) + (size_t)row * 8192;
    #pragma unroll
    for (int it = 0; it < 4; ++it) {
        const int base = it * 2048 + tid * 8;
        const float4 f0 = *(const float4*)(src + base);
        const float4 f1 = *(const float4*)(src + base + 4);
        uint4 p;
        p.x = (unsigned)f2bf(f0.x * scale) | ((unsigned)f2bf(f0.y * scale) << 16);
        p.y = (unsigned)f2bf(f0.z * scale) | ((unsigned)f2bf(f0.w * scale) << 16);
        p.z = (unsigned)f2bf(f1.x * scale) | ((unsigned)f2bf(f1.y * scale) << 16);
        p.w = (unsigned)f2bf(f1.z * scale) | ((unsigned)f2bf(f1.w * scale) << 16);
        *(uint4*)(dst + base) = p;
    }
}

// ---------------- main: per-v 2048x2048x256 bf16 GEMM + exp + reductions -----
// LDS: unpadded [128 rows][64 bf16] per operand, XOR-swizzled colgroups:
//   physical cg = logical cg ^ (row & 7)   (cg = 16B group, 8 per row)
__global__ __launch_bounds__(256) void infonce_main_fast(
    const unsigned short* __restrict__ pA, const unsigned short* __restrict__ pB,
    float* __restrict__ total, float* __restrict__ selfp, float* __restrict__ ap)
{
    __shared__ __align__(16) unsigned short As[128 * 64];
    __shared__ __align__(16) unsigned short Bs[128 * 64];
    __shared__ float ls_row[128];
    __shared__ float ls_col[128];

    const int tid  = threadIdx.x;
    const int lane = tid & 63;
    const int w    = tid >> 6;        // wave 0..3
    const int wm   = w >> 1;
    const int wn   = w & 1;
    const int lrow = lane & 15;
    const int quad = lane >> 4;

    const int tileM = blockIdx.x & 15;
    const int tileN = blockIdx.x >> 4;
    const int v     = blockIdx.y;
    const bool diag = (tileM >> 1) == (tileN >> 1);   // i == j (256-row batches)

    if (tid < 128) ls_row[tid] = 0.f;
    else           ls_col[tid - 128] = 0.f;

    // staging: wave w stages rows [w*32, w*32+32) of both tiles
    const int row8 = lane >> 3;          // 0..7
    const int cg   = (lane & 7) ^ row8;  // logical colgroup this lane fetches
    const unsigned short* aRow =
        pA + ((size_t)(tileM * 128 + w * 32 + row8) * 32 + v) * 256 + cg * 8;
    const unsigned short* bRow =
        pB + ((size_t)(tileN * 128 + w * 32 + row8) * 32 + v) * 256 + cg * 8;

    f32x4 acc[4][4];
    #pragma unroll
    for (int i = 0; i < 4; ++i)
        #pragma unroll
        for (int j = 0; j < 4; ++j)
            acc[i][j] = (f32x4){0.f, 0.f, 0.f, 0.f};

    const int swz = lrow & 7;

    for (int s = 0; s < 4; ++s) {
        if (s) __syncthreads();
        #pragma unroll
        for (int issue = 0; issue < 4; ++issue) {
            async16(aRow + (size_t)issue * 8 * 8192 + s * 64,
                    &As[(w * 32 + issue * 8) * 64]);
            async16(bRow + (size_t)issue * 8 * 8192 + s * 64,
                    &Bs[(w * 32 + issue * 8) * 64]);
        }
        __syncthreads();   // compiler drains vmcnt here
        #pragma unroll
        for (int kh = 0; kh < 2; ++kh) {
            bf16x8 af[4], bfr[4];
            #pragma unroll
            for (int t = 0; t < 4; ++t) {
                const int rA = wm * 64 + t * 16 + lrow;
                const int rB = wn * 64 + t * 16 + lrow;
                const int pc = (((kh << 2) + quad) ^ swz) * 8;
                af[t]  = *(const bf16x8*)&As[rA * 64 + pc];
                bfr[t] = *(const bf16x8*)&Bs[rB * 64 + pc];
            }
            #pragma unroll
            for (int ti = 0; ti < 4; ++ti)
                #pragma unroll
                for (int tj = 0; tj < 4; ++tj)
                    acc[ti][tj] = __builtin_amdgcn_mfma_f32_16x16x32_bf16(
                        af[ti], bfr[tj], acc[ti][tj], 0, 0, 0);
        }
    }

    // Epilogue. acc holds log2(e)*score; E = exp2(acc).
    // C/D layout per 16x16 tile: col = lane&15, row = quad*4 + reg.
    if (diag) {
        float colp[4] = {0.f, 0.f, 0.f, 0.f};
        #pragma unroll
        for (int ti = 0; ti < 4; ++ti) {
            #pragma unroll
            for (int r = 0; r < 4; ++r) {
                float e0 = EXP2(acc[ti][0][r]);
                float e1 = EXP2(acc[ti][1][r]);
                float e2 = EXP2(acc[ti][2][r]);
                float e3 = EXP2(acc[ti][3][r]);
                colp[0] += e0; colp[1] += e1; colp[2] += e2; colp[3] += e3;
                float rp = (e0 + e1) + (e2 + e3);
                rp += __shfl_xor(rp, 1);
                rp += __shfl_xor(rp, 2);
                rp += __shfl_xor(rp, 4);
                rp += __shfl_xor(rp, 8);
                if (lrow == 0)
                    atomicAdd(&ls_row[wm * 64 + ti * 16 + quad * 4 + r], rp);
            }
        }
        #pragma unroll
        for (int tj = 0; tj < 4; ++tj) {
            float q = colp[tj];
            q += __shfl_xor(q, 16);
            q += __shfl_xor(q, 32);
            if (lane < 16)
                atomicAdd(&ls_col[wn * 64 + tj * 16 + lane], q);
        }
    } else {
        #pragma unroll
        for (int ti = 0; ti < 4; ++ti) {
            #pragma unroll
            for (int r = 0; r < 4; ++r) {
                float e0 = EXP2(acc[ti][0][r]);
                float e1 = EXP2(acc[ti][1][r]);
                float e2 = EXP2(acc[ti][2][r]);
                float e3 = EXP2(acc[ti][3][r]);
                float rp = (e0 + e1) + (e2 + e3);
                rp += __shfl_xor(rp, 1);
                rp += __shfl_xor(rp, 2);
                rp += __shfl_xor(rp, 4);
                rp += __shfl_xor(rp, 8);
                if (lrow == 0)
                    atomicAdd(&ls_row[wm * 64 + ti * 16 + quad * 4 + r], rp);
            }
        }
    }
    __syncthreads();
    if (tid < 128) {
        const float rs = ls_row[tid];
        const int rowg = tileM * 128 + tid;           // = i*T + q
        atomicAdd(&total[rowg], rs);
        if (diag) atomicAdd(&selfp[rowg], rs);
    } else if (diag) {
        const int t2 = tid - 128;
        atomicAdd(&ap[tileN * 128 + t2], ls_col[t2]); // col index = i*T + k on diag
    }
}

// ---------------- fallback main (round-1 kernel, fp32 staging) ---------------
__global__ __launch_bounds__(256) void infonce_main_slow(
    const float* __restrict__ feat, const float* __restrict__ feat_aug,
    float* __restrict__ total, float* __restrict__ selfp, float* __restrict__ ap)
{
    __shared__ __align__(16) unsigned short As[128][72];
    __shared__ __align__(16) unsigned short Bs[128][72];
    __shared__ float ls_row[128];
    __shared__ float ls_col[128];

    const int tid  = threadIdx.x;
    const int lane = tid & 63;
    const int w    = tid >> 6;
    const int wm   = w >> 1;
    const int wn   = w & 1;
    const int lrow = lane & 15;
    const int quad = lane >> 4;

    const int tileM = blockIdx.x & 15;
    const int tileN = blockIdx.x >> 4;
    const int v     = blockIdx.y;
    const bool diag = (tileM >> 1) == (tileN >> 1);

    if (tid < 128) ls_row[tid] = 0.0f;
    else           ls_col[tid - 128] = 0.0f;

    const float* aBase = feat     + (size_t)v * 256;
    const float* bBase = feat_aug + (size_t)v * 256;

    f32x4 acc[4][4];
    #pragma unroll
    for (int i = 0; i < 4; ++i)
        #pragma unroll
        for (int j = 0; j < 4; ++j)
            acc[i][j] = (f32x4){0.f, 0.f, 0.f, 0.f};

    const int srow = tid >> 4;
    const int scol = (tid & 15) * 4;

    for (int s = 0; s < 4; ++s) {
        const int k0 = s * 64;
        if (s) __syncthreads();
        #pragma unroll
        for (int it = 0; it < 8; ++it) {
            const int row = it * 16 + srow;
            const float4 a4 = *(const float4*)(aBase + (size_t)(tileM * 128 + row) * 8192 + k0 + scol);
            const float4 b4 = *(const float4*)(bBase + (size_t)(tileN * 128 + row) * 8192 + k0 + scol);
            uint2 wa, wb;
            wa.x = (unsigned)f2bf(a4.x) | ((unsigned)f2bf(a4.y) << 16);
            wa.y = (unsigned)f2bf(a4.z) | ((unsigned)f2bf(a4.w) << 16);
            wb.x = (unsigned)f2bf(b4.x) | ((unsigned)f2bf(b4.y) << 16);
            wb.y = (unsigned)f2bf(b4.z) | ((unsigned)f2bf(b4.w) << 16);
            *(uint2*)&As[row][scol] = wa;
            *(uint2*)&Bs[row][scol] = wb;
        }
        __syncthreads();
        #pragma unroll
        for (int kk = 0; kk < 64; kk += 32) {
            bf16x8 af[4], bfr[4];
            #pragma unroll
            for (int t = 0; t < 4; ++t) {
                af[t]  = *(const bf16x8*)&As[wm * 64 + t * 16 + lrow][kk + quad * 8];
                bfr[t] = *(const bf16x8*)&Bs[wn * 64 + t * 16 + lrow][kk + quad * 8];
            }
            #pragma unroll
            for (int ti = 0; ti < 4; ++ti)
                #pragma unroll
                for (int tj = 0; tj < 4; ++tj)
                    acc[ti][tj] = __builtin_amdgcn_mfma_f32_16x16x32_bf16(
                        af[ti], bfr[tj], acc[ti][tj], 0, 0, 0);
        }
    }

    float colp[4] = {0.f, 0.f, 0.f, 0.f};
    #pragma unroll
    for (int ti = 0; ti < 4; ++ti) {
        #pragma unroll
        for (int r = 0; r < 4; ++r) {
            float e0 = __expf(acc[ti][0][r]);
            float e1 = __expf(acc[ti][1][r]);
            float e2 = __expf(acc[ti][2][r]);
            float e3 = __expf(acc[ti][3][r]);
            colp[0] += e0; colp[1] += e1; colp[2] += e2; colp[3] += e3;
            float rp = (e0 + e1) + (e2 + e3);
            rp += __shfl_xor(rp, 1);
            rp += __shfl_xor(rp, 2);
            rp += __shfl_xor(rp, 4);
            rp += __shfl_xor(rp, 8);
            if (lrow == 0)
                atomicAdd(&ls_row[wm * 64 + ti * 16 + quad * 4 + r], rp);
        }
    }
    if (diag) {
        #pragma unroll
        for (int tj = 0; tj < 4; ++tj) {
            float q = colp[tj];
            q += __shfl_xor(q, 16);
            q += __shfl_xor(q, 32);
            if (lane < 16)
                atomicAdd(&ls_col[wn * 64 + tj * 16 + lane], q);
        }
    }
    __syncthreads();
    if (tid < 128) {
        const float rs = ls_row[tid];
        const int rowg = tileM * 128 + tid;
        atomicAdd(&total[rowg], rs);
        if (diag) atomicAdd(&selfp[rowg], rs);
    } else if (diag) {
        const int t2 = tid - 128;
        atomicAdd(&ap[tileN * 128 + t2], ls_col[t2]);
    }
}

__global__ __launch_bounds__(256) void infonce_finalize(
    const float* __restrict__ total, const float* __restrict__ selfp,
    const float* __restrict__ ap, float* __restrict__ out)
{
    __shared__ float red[4];
    const int tid = threadIdx.x;
    float s = 0.f;
    for (int e = tid; e < 2048; e += 256) {
        const float an = total[e] - selfp[e];
        s += logf(an / ap[e]);
    }
    #pragma unroll
    for (int m = 32; m >= 1; m >>= 1) s += __shfl_xor(s, m);
    if ((tid & 63) == 0) red[tid >> 6] = s;
    __syncthreads();
    if (tid == 0) out[0] = (red[0] + red[1] + red[2] + red[3]) * (1.0f / 256.0f);
}

extern "C" void kernel_launch(void* const* d_in, const int* in_sizes, int n_in,
                              void* d_out, int out_size, void* d_ws, size_t ws_size,
                              hipStream_t stream) {
    const float* feat     = (const float*)d_in[0];
    const float* feat_aug = (const float*)d_in[1];
    float* total = (float*)d_ws;
    float* selfp = total + 2048;
    float* ap    = selfp + 2048;
    hipMemsetAsync(d_ws, 0, 3 * 2048 * sizeof(float), stream);

    const size_t packElems = (size_t)2048 * 8192;                  // per tensor
    const size_t need = 32768 + 2 * packElems * sizeof(unsigned short);
    if (ws_size >= need) {
        unsigned short* pA = (unsigned short*)((char*)d_ws + 32768);
        unsigned short* pB = pA + packElems;
        infonce_repack<<<dim3(2048, 2), 256, 0, stream>>>(feat, feat_aug, pA, pB);
        infonce_main_fast<<<dim3(256, 32), 256, 0, stream>>>(pA, pB, total, selfp, ap);
    } else {
        infonce_main_slow<<<dim3(256, 32), 256, 0, stream>>>(feat, feat_aug, total, selfp, ap);
    }
    infonce_finalize<<<1, 256, 0, stream>>>(total, selfp, ap, (float*)d_out);
}

// Round 5
// 259.874 us; speedup vs baseline: 1.0065x; 1.0065x over previous
//
#include <hip/hip_runtime.h>
#include <hip/hip_bf16.h>

// Problem: B=8, T=256, V=32, D=256.
// Per-v GEMM: M=N=2048 (rows = i*T+q / j*T+k), K=256, then exp + 3 reductions.
// feature[B,T,V,D]: element (row, v, d) at feat[(row*32 + v)*256 + d].
// Fast path: inputs repacked to fp8 e4m3 (same [row][v][d] layout, A prescaled
// by log2(e)); main GEMM uses mfma_f32_16x16x32_fp8_fp8 with double-buffered
// LDS (8 KB/tile) and cross-stage global_load_lds prefetch.

typedef __attribute__((ext_vector_type(4))) float f32x4;
typedef __attribute__((ext_vector_type(8))) __bf16 bf16x8;   // fallback path
typedef long long i64;

#if __has_builtin(__builtin_amdgcn_exp2f)
#define EXP2(x) __builtin_amdgcn_exp2f(x)
#else
#define EXP2(x) exp2f(x)
#endif

__device__ __forceinline__ unsigned short f2bf(float f) {
    unsigned u = __builtin_bit_cast(unsigned, f);
    u += 0x7FFFu + ((u >> 16) & 1u);   // RNE (no NaNs in data)
    return (unsigned short)(u >> 16);
}

// hi word-select must be an immediate -> template parameter
template <bool HI>
__device__ __forceinline__ unsigned cvt2fp8(float a, float b, unsigned old) {
    return __builtin_amdgcn_cvt_pk_fp8_f32(a, b, old, HI);
}
__device__ __forceinline__ unsigned pack4fp8(float x, float y, float z, float w) {
    return cvt2fp8<true>(z, w, cvt2fp8<false>(x, y, 0u));
}

__device__ __forceinline__ void async16(const void* g, void* l) {
    __builtin_amdgcn_global_load_lds(
        (const __attribute__((address_space(1))) unsigned int*)g,
        (__attribute__((address_space(3))) unsigned int*)l,
        16, 0, 0);
}

// ------------- repack: streaming fp32 -> fp8 e4m3 (same layout) --------------
// grid (2048, 2): one row (8192 floats -> 8192 bytes) per block; y = tensor.
// A (feature) prescaled by log2(e) so the epilogue exp is bare v_exp_f32.
__global__ __launch_bounds__(256) void infonce_repack_fp8(
    const float* __restrict__ feat, const float* __restrict__ feat_aug,
    unsigned char* __restrict__ pA, unsigned char* __restrict__ pB)
{
    const int row = blockIdx.x;
    const int tid = threadIdx.x;
    const bool isA = (blockIdx.y == 0);
    const float sc = isA ? 1.4426950408889634f : 1.0f;
    const float* src = (isA ? feat : feat_aug) + (size_t)row * 8192;
    unsigned char* dst = (isA ? pA : pB) + (size_t)row * 8192;
    #pragma unroll
    for (int it = 0; it < 2; ++it) {
        const int base = it * 4096 + tid * 16;
        const float4 f0 = *(const float4*)(src + base);
        const float4 f1 = *(const float4*)(src + base + 4);
        const float4 f2 = *(const float4*)(src + base + 8);
        const float4 f3 = *(const float4*)(src + base + 12);
        uint4 p;
        p.x = pack4fp8(f0.x*sc, f0.y*sc, f0.z*sc, f0.w*sc);
        p.y = pack4fp8(f1.x*sc, f1.y*sc, f1.z*sc, f1.w*sc);
        p.z = pack4fp8(f2.x*sc, f2.y*sc, f2.z*sc, f2.w*sc);
        p.w = pack4fp8(f3.x*sc, f3.y*sc, f3.z*sc, f3.w*sc);
        *(uint4*)(dst + base) = p;
    }
}

// ------- main: per-v 2048x2048x256 fp8 GEMM + exp + reductions, dbuf --------
// LDS per buffer: slab-major — slab cg (16-byte column group, 4 per 64-elt
// stage) at offset cg*2048, row r at +r*16. ds_read_b64 pattern is 2 words/
// bank per 32-lane phase (conflict-free per m136). Wave w stages cg=w.
__global__ __launch_bounds__(256) void infonce_main_fp8(
    const unsigned char* __restrict__ pA, const unsigned char* __restrict__ pB,
    float* __restrict__ total, float* __restrict__ selfp, float* __restrict__ ap)
{
    __shared__ __align__(16) unsigned char As[2][8192];
    __shared__ __align__(16) unsigned char Bs[2][8192];
    __shared__ float ls_row[128];
    __shared__ float ls_col[128];

    const int tid  = threadIdx.x;
    const int lane = tid & 63;
    const int w    = tid >> 6;        // wave 0..3
    const int wm   = w >> 1;
    const int wn   = w & 1;
    const int lrow = lane & 15;
    const int quad = lane >> 4;

    const int tileM = blockIdx.x & 15;
    const int tileN = blockIdx.x >> 4;
    const int v     = blockIdx.y;
    const bool diag = (tileM >> 1) == (tileN >> 1);   // i == j (256-row batches)

    if (tid < 128) ls_row[tid] = 0.f;
    else           ls_col[tid - 128] = 0.f;

    // global: row stride 8192 B; wave w fetches bytes [s*64 + w*16, +16) of
    // rows i*64+lane (i = 0,1) for both operands.
    const unsigned char* aG = pA + ((size_t)(tileM*128 + lane) * 32 + v) * 256 + w * 16;
    const unsigned char* bG = pB + ((size_t)(tileN*128 + lane) * 32 + v) * 256 + w * 16;

    f32x4 acc[4][4];
    #pragma unroll
    for (int i = 0; i < 4; ++i)
        #pragma unroll
        for (int j = 0; j < 4; ++j)
            acc[i][j] = (f32x4){0.f, 0.f, 0.f, 0.f};

    // prologue: stage 0 -> buffer 0
    #pragma unroll
    for (int i = 0; i < 2; ++i) {
        async16(aG + (size_t)i * 64 * 8192, &As[0][w * 2048 + i * 1024]);
        async16(bG + (size_t)i * 64 * 8192, &Bs[0][w * 2048 + i * 1024]);
    }
    __syncthreads();

    for (int s = 0; s < 4; ++s) {
        const int b = s & 1;
        if (s < 3) {
            const int nb = b ^ 1;
            #pragma unroll
            for (int i = 0; i < 2; ++i) {
                async16(aG + (size_t)i * 64 * 8192 + (s + 1) * 64,
                        &As[nb][w * 2048 + i * 1024]);
                async16(bG + (size_t)i * 64 * 8192 + (s + 1) * 64,
                        &Bs[nb][w * 2048 + i * 1024]);
            }
        }
        #pragma unroll
        for (int kh = 0; kh < 2; ++kh) {
            i64 af[4], bf[4];
            const int slab = (kh * 2 + (quad >> 1)) * 2048 + (quad & 1) * 8;
            #pragma unroll
            for (int t = 0; t < 4; ++t) {
                af[t] = *(const i64*)&As[b][slab + (wm * 64 + t * 16 + lrow) * 16];
                bf[t] = *(const i64*)&Bs[b][slab + (wn * 64 + t * 16 + lrow) * 16];
            }
            #pragma unroll
            for (int ti = 0; ti < 4; ++ti)
                #pragma unroll
                for (int tj = 0; tj < 4; ++tj)
                    acc[ti][tj] = __builtin_amdgcn_mfma_f32_16x16x32_fp8_fp8(
                        af[ti], bf[tj], acc[ti][tj], 0, 0, 0);
        }
        __syncthreads();   // drains prefetch (landed during compute) + buf reuse
    }

    // Epilogue. acc holds log2(e)*score; E = exp2(acc).
    // C/D layout per 16x16 tile: col = lane&15, row = quad*4 + reg.
    if (diag) {
        float colp[4] = {0.f, 0.f, 0.f, 0.f};
        #pragma unroll
        for (int ti = 0; ti < 4; ++ti) {
            #pragma unroll
            for (int r = 0; r < 4; ++r) {
                float e0 = EXP2(acc[ti][0][r]);
                float e1 = EXP2(acc[ti][1][r]);
                float e2 = EXP2(acc[ti][2][r]);
                float e3 = EXP2(acc[ti][3][r]);
                colp[0] += e0; colp[1] += e1; colp[2] += e2; colp[3] += e3;
                float rp = (e0 + e1) + (e2 + e3);
                rp += __shfl_xor(rp, 1);
                rp += __shfl_xor(rp, 2);
                rp += __shfl_xor(rp, 4);
                rp += __shfl_xor(rp, 8);
                if (lrow == 0)
                    atomicAdd(&ls_row[wm * 64 + ti * 16 + quad * 4 + r], rp);
            }
        }
        #pragma unroll
        for (int tj = 0; tj < 4; ++tj) {
            float q = colp[tj];
            q += __shfl_xor(q, 16);
            q += __shfl_xor(q, 32);
            if (lane < 16)
                atomicAdd(&ls_col[wn * 64 + tj * 16 + lane], q);
        }
    } else {
        #pragma unroll
        for (int ti = 0; ti < 4; ++ti) {
            #pragma unroll
            for (int r = 0; r < 4; ++r) {
                float e0 = EXP2(acc[ti][0][r]);
                float e1 = EXP2(acc[ti][1][r]);
                float e2 = EXP2(acc[ti][2][r]);
                float e3 = EXP2(acc[ti][3][r]);
                float rp = (e0 + e1) + (e2 + e3);
                rp += __shfl_xor(rp, 1);
                rp += __shfl_xor(rp, 2);
                rp += __shfl_xor(rp, 4);
                rp += __shfl_xor(rp, 8);
                if (lrow == 0)
                    atomicAdd(&ls_row[wm * 64 + ti * 16 + quad * 4 + r], rp);
            }
        }
    }
    __syncthreads();
    if (tid < 128) {
        const float rs = ls_row[tid];
        const int rowg = tileM * 128 + tid;           // = i*T + q
        atomicAdd(&total[rowg], rs);
        if (diag) atomicAdd(&selfp[rowg], rs);
    } else if (diag) {
        const int t2 = tid - 128;
        atomicAdd(&ap[tileN * 128 + t2], ls_col[t2]); // col index = i*T + k on diag
    }
}

// ---------------- fallback main (round-1 kernel, fp32 staging) ---------------
__global__ __launch_bounds__(256) void infonce_main_slow(
    const float* __restrict__ feat, const float* __restrict__ feat_aug,
    float* __restrict__ total, float* __restrict__ selfp, float* __restrict__ ap)
{
    __shared__ __align__(16) unsigned short As[128][72];
    __shared__ __align__(16) unsigned short Bs[128][72];
    __shared__ float ls_row[128];
    __shared__ float ls_col[128];

    const int tid  = threadIdx.x;
    const int lane = tid & 63;
    const int w    = tid >> 6;
    const int wm   = w >> 1;
    const int wn   = w & 1;
    const int lrow = lane & 15;
    const int quad = lane >> 4;

    const int tileM = blockIdx.x & 15;
    const int tileN = blockIdx.x >> 4;
    const int v     = blockIdx.y;
    const bool diag = (tileM >> 1) == (tileN >> 1);

    if (tid < 128) ls_row[tid] = 0.0f;
    else           ls_col[tid - 128] = 0.0f;

    const float* aBase = feat     + (size_t)v * 256;
    const float* bBase = feat_aug + (size_t)v * 256;

    f32x4 acc[4][4];
    #pragma unroll
    for (int i = 0; i < 4; ++i)
        #pragma unroll
        for (int j = 0; j < 4; ++j)
            acc[i][j] = (f32x4){0.f, 0.f, 0.f, 0.f};

    const int srow = tid >> 4;
    const int scol = (tid & 15) * 4;

    for (int s = 0; s < 4; ++s) {
        const int k0 = s * 64;
        if (s) __syncthreads();
        #pragma unroll
        for (int it = 0; it < 8; ++it) {
            const int row = it * 16 + srow;
            const float4 a4 = *(const float4*)(aBase + (size_t)(tileM * 128 + row) * 8192 + k0 + scol);
            const float4 b4 = *(const float4*)(bBase + (size_t)(tileN * 128 + row) * 8192 + k0 + scol);
            uint2 wa, wb;
            wa.x = (unsigned)f2bf(a4.x) | ((unsigned)f2bf(a4.y) << 16);
            wa.y = (unsigned)f2bf(a4.z) | ((unsigned)f2bf(a4.w) << 16);
            wb.x = (unsigned)f2bf(b4.x) | ((unsigned)f2bf(b4.y) << 16);
            wb.y = (unsigned)f2bf(b4.z) | ((unsigned)f2bf(b4.w) << 16);
            *(uint2*)&As[row][scol] = wa;
            *(uint2*)&Bs[row][scol] = wb;
        }
        __syncthreads();
        #pragma unroll
        for (int kk = 0; kk < 64; kk += 32) {
            bf16x8 af[4], bfr[4];
            #pragma unroll
            for (int t = 0; t < 4; ++t) {
                af[t]  = *(const bf16x8*)&As[wm * 64 + t * 16 + lrow][kk + quad * 8];
                bfr[t] = *(const bf16x8*)&Bs[wn * 64 + t * 16 + lrow][kk + quad * 8];
            }
            #pragma unroll
            for (int ti = 0; ti < 4; ++ti)
                #pragma unroll
                for (int tj = 0; tj < 4; ++tj)
                    acc[ti][tj] = __builtin_amdgcn_mfma_f32_16x16x32_bf16(
                        af[ti], bfr[tj], acc[ti][tj], 0, 0, 0);
        }
    }

    float colp[4] = {0.f, 0.f, 0.f, 0.f};
    #pragma unroll
    for (int ti = 0; ti < 4; ++ti) {
        #pragma unroll
        for (int r = 0; r < 4; ++r) {
            float e0 = __expf(acc[ti][0][r]);
            float e1 = __expf(acc[ti][1][r]);
            float e2 = __expf(acc[ti][2][r]);
            float e3 = __expf(acc[ti][3][r]);
            colp[0] += e0; colp[1] += e1; colp[2] += e2; colp[3] += e3;
            float rp = (e0 + e1) + (e2 + e3);
            rp += __shfl_xor(rp, 1);
            rp += __shfl_xor(rp, 2);
            rp += __shfl_xor(rp, 4);
            rp += __shfl_xor(rp, 8);
            if (lrow == 0)
                atomicAdd(&ls_row[wm * 64 + ti * 16 + quad * 4 + r], rp);
        }
    }
    if (diag) {
        #pragma unroll
        for (int tj = 0; tj < 4; ++tj) {
            float q = colp[tj];
            q += __shfl_xor(q, 16);
            q += __shfl_xor(q, 32);
            if (lane < 16)
                atomicAdd(&ls_col[wn * 64 + tj * 16 + lane], q);
        }
    }
    __syncthreads();
    if (tid < 128) {
        const float rs = ls_row[tid];
        const int rowg = tileM * 128 + tid;
        atomicAdd(&total[rowg], rs);
        if (diag) atomicAdd(&selfp[rowg], rs);
    } else if (diag) {
        const int t2 = tid - 128;
        atomicAdd(&ap[tileN * 128 + t2], ls_col[t2]);
    }
}

__global__ __launch_bounds__(256) void infonce_finalize(
    const float* __restrict__ total, const float* __restrict__ selfp,
    const float* __restrict__ ap, float* __restrict__ out)
{
    __shared__ float red[4];
    const int tid = threadIdx.x;
    float s = 0.f;
    for (int e = tid; e < 2048; e += 256) {
        const float an = total[e] - selfp[e];
        s += logf(an / ap[e]);
    }
    #pragma unroll
    for (int m = 32; m >= 1; m >>= 1) s += __shfl_xor(s, m);
    if ((tid & 63) == 0) red[tid >> 6] = s;
    __syncthreads();
    if (tid == 0) out[0] = (red[0] + red[1] + red[2] + red[3]) * (1.0f / 256.0f);
}

extern "C" void kernel_launch(void* const* d_in, const int* in_sizes, int n_in,
                              void* d_out, int out_size, void* d_ws, size_t ws_size,
                              hipStream_t stream) {
    const float* feat     = (const float*)d_in[0];
    const float* feat_aug = (const float*)d_in[1];
    float* total = (float*)d_ws;
    float* selfp = total + 2048;
    float* ap    = selfp + 2048;
    (void)hipMemsetAsync(d_ws, 0, 3 * 2048 * sizeof(float), stream);

    const size_t packBytes = (size_t)2048 * 8192;                  // per tensor, fp8
    const size_t need = 32768 + 2 * packBytes;
    if (ws_size >= need) {
        unsigned char* pA = (unsigned char*)d_ws + 32768;
        unsigned char* pB = pA + packBytes;
        infonce_repack_fp8<<<dim3(2048, 2), 256, 0, stream>>>(feat, feat_aug, pA, pB);
        infonce_main_fp8<<<dim3(256, 32), 256, 0, stream>>>(pA, pB, total, selfp, ap);
    } else {
        infonce_main_slow<<<dim3(256, 32), 256, 0, stream>>>(feat, feat_aug, total, selfp, ap);
    }
    infonce_finalize<<<1, 256, 0, stream>>>(total, selfp, ap, (float*)d_out);
}

// Round 6
// 207.550 us; speedup vs baseline: 1.2602x; 1.2521x over previous
//
#include <hip/hip_runtime.h>
#include <hip/hip_bf16.h>

// Problem: B=8, T=256, V=32, D=256.
// Per-v GEMM: M=N=2048 (rows = i*T+q / j*T+k), K=256, then exp + 3 reductions.
// feature[B,T,V,D]: element (row, v, d) at feat[(row*32 + v)*256 + d].
// Fast path: inputs repacked to fp8 e4m3 with a K-PERMUTED layout: within each
// 64-col stage, 16-byte group g holds original k-octets (g, g+4). One
// ds_read_b128 then yields the fragments for BOTH kh MFMAs. A prescaled by
// log2(e). Row-sum reductions use DPP (VALU) instead of ds_bpermute.

typedef __attribute__((ext_vector_type(4))) float f32x4;
typedef __attribute__((ext_vector_type(2))) long long i64x2;
typedef __attribute__((ext_vector_type(8))) __bf16 bf16x8;   // fallback path
typedef long long i64;

#if __has_builtin(__builtin_amdgcn_exp2f)
#define EXP2(x) __builtin_amdgcn_exp2f(x)
#else
#define EXP2(x) exp2f(x)
#endif

__device__ __forceinline__ unsigned short f2bf(float f) {
    unsigned u = __builtin_bit_cast(unsigned, f);
    u += 0x7FFFu + ((u >> 16) & 1u);   // RNE (no NaNs in data)
    return (unsigned short)(u >> 16);
}

template <bool HI>
__device__ __forceinline__ unsigned cvt2fp8(float a, float b, unsigned old) {
    return __builtin_amdgcn_cvt_pk_fp8_f32(a, b, old, HI);
}
__device__ __forceinline__ unsigned pack4fp8(float x, float y, float z, float w) {
    return cvt2fp8<true>(z, w, cvt2fp8<false>(x, y, 0u));
}

__device__ __forceinline__ void async16(const void* g, void* l) {
    __builtin_amdgcn_global_load_lds(
        (const __attribute__((address_space(1))) unsigned int*)g,
        (__attribute__((address_space(3))) unsigned int*)l,
        16, 0, 0);
}

// DPP row-sum over 16-lane rows; full sum lands in lane 15 of each row.
template <int CTRL>
__device__ __forceinline__ float dpp_add(float x) {
    int y = __builtin_amdgcn_update_dpp(0, __builtin_bit_cast(int, x),
                                        CTRL, 0xf, 0xf, true);
    return x + __builtin_bit_cast(float, y);
}
__device__ __forceinline__ float rowsum16(float x) {
    x = dpp_add<0x111>(x);   // row_shr:1
    x = dpp_add<0x112>(x);   // row_shr:2
    x = dpp_add<0x114>(x);   // row_shr:4
    x = dpp_add<0x118>(x);   // row_shr:8
    return x;
}

// ---- repack: fp32 -> fp8 e4m3, K-permuted (group g = octets g, g+4) --------
// grid (2048, 2): one row (8192 floats -> 8192 bytes) per block; y = tensor.
// Block (0,0) also zeroes the 3*2048 counter floats (replaces memset dispatch).
__global__ __launch_bounds__(256) void infonce_repack_fp8(
    const float* __restrict__ feat, const float* __restrict__ feat_aug,
    unsigned char* __restrict__ pA, unsigned char* __restrict__ pB,
    float* __restrict__ counters)
{
    const int row = blockIdx.x;
    const int tid = threadIdx.x;
    if (blockIdx.x == 0 && blockIdx.y == 0) {
        #pragma unroll
        for (int k = 0; k < 24; ++k) counters[k * 256 + tid] = 0.f;
    }
    const bool isA = (blockIdx.y == 0);
    const float sc = isA ? 1.4426950408889634f : 1.0f;
    const float* src = (isA ? feat : feat_aug) + (size_t)row * 8192;
    unsigned char* dst = (isA ? pA : pB) + (size_t)row * 8192;
    #pragma unroll
    for (int it = 0; it < 2; ++it) {
        const int ob = it * 4096 + tid * 16;        // out byte in this row
        const int v = ob >> 8;
        const int s = (ob >> 6) & 3;
        const int g = (ob >> 4) & 3;
        const int f1 = v * 256 + s * 64 + g * 8;    // octet g
        const int f2 = f1 + 32;                     // octet g+4
        const float4 a0 = *(const float4*)(src + f1);
        const float4 a1 = *(const float4*)(src + f1 + 4);
        const float4 b0 = *(const float4*)(src + f2);
        const float4 b1 = *(const float4*)(src + f2 + 4);
        uint4 p;
        p.x = pack4fp8(a0.x*sc, a0.y*sc, a0.z*sc, a0.w*sc);
        p.y = pack4fp8(a1.x*sc, a1.y*sc, a1.z*sc, a1.w*sc);
        p.z = pack4fp8(b0.x*sc, b0.y*sc, b0.z*sc, b0.w*sc);
        p.w = pack4fp8(b1.x*sc, b1.y*sc, b1.z*sc, b1.w*sc);
        *(uint4*)(dst + ob) = p;
    }
}

// ------- main: per-v 2048x2048x256 fp8 GEMM + exp + reductions, dbuf --------
// LDS per buffer: [128 rows][4 slots of 16 B], row stride 64 B. Slot s_ of row
// r holds global cg (s_ ^ ((r>>1)&3)) — zero-conflict b128 read pattern.
__global__ __launch_bounds__(256) void infonce_main_fp8(
    const unsigned char* __restrict__ pA, const unsigned char* __restrict__ pB,
    float* __restrict__ total, float* __restrict__ selfp, float* __restrict__ ap)
{
    __shared__ __align__(16) unsigned char As[2][8192];
    __shared__ __align__(16) unsigned char Bs[2][8192];
    __shared__ float ls_row2[2][128];
    __shared__ float ls_col2[2][128];

    const int tid  = threadIdx.x;
    const int lane = tid & 63;
    const int w    = tid >> 6;        // wave 0..3
    const int wm   = w >> 1;
    const int wn   = w & 1;
    const int lrow = lane & 15;
    const int quad = lane >> 4;

    const int tileM = blockIdx.x & 15;
    const int tileN = blockIdx.x >> 4;
    const int v     = blockIdx.y;
    const bool diag = (tileM >> 1) == (tileN >> 1);   // i == j (256-row batches)

    // staging: wave w, issue i covers rows [w*32+i*16, +16); lane l -> local
    // row +(l>>2), slot l&3 holding global cg (l&3)^((l>>3)&3).
    const int rl  = w * 32 + (lane >> 2);
    const int cgg = (lane & 3) ^ ((lane >> 3) & 3);
    const unsigned char* aG = pA + ((size_t)(tileM*128 + rl) * 32 + v) * 256 + cgg * 16;
    const unsigned char* bG = pB + ((size_t)(tileN*128 + rl) * 32 + v) * 256 + cgg * 16;

    f32x4 acc[4][4];
    #pragma unroll
    for (int i = 0; i < 4; ++i)
        #pragma unroll
        for (int j = 0; j < 4; ++j)
            acc[i][j] = (f32x4){0.f, 0.f, 0.f, 0.f};

    // prologue: stage 0 -> buffer 0
    #pragma unroll
    for (int i = 0; i < 2; ++i) {
        async16(aG + (size_t)i * 16 * 8192, &As[0][w * 2048 + i * 1024]);
        async16(bG + (size_t)i * 16 * 8192, &Bs[0][w * 2048 + i * 1024]);
    }
    __syncthreads();

    const int cgp = (quad ^ ((lrow >> 1) & 3)) * 16;   // physical slot byte off

    #pragma unroll
    for (int s = 0; s < 4; ++s) {
        const int b = s & 1;
        if (s < 3) {
            const int nb = b ^ 1;
            #pragma unroll
            for (int i = 0; i < 2; ++i) {
                async16(aG + (size_t)i * 16 * 8192 + (s + 1) * 64,
                        &As[nb][w * 2048 + i * 1024]);
                async16(bG + (size_t)i * 16 * 8192 + (s + 1) * 64,
                        &Bs[nb][w * 2048 + i * 1024]);
            }
        }
        i64x2 a4[4], b4[4];
        #pragma unroll
        for (int t = 0; t < 4; ++t) {
            a4[t] = *(const i64x2*)&As[b][(wm * 64 + t * 16 + lrow) * 64 + cgp];
            b4[t] = *(const i64x2*)&Bs[b][(wn * 64 + t * 16 + lrow) * 64 + cgp];
        }
        #pragma unroll
        for (int kh = 0; kh < 2; ++kh)
            #pragma unroll
            for (int ti = 0; ti < 4; ++ti)
                #pragma unroll
                for (int tj = 0; tj < 4; ++tj)
                    acc[ti][tj] = __builtin_amdgcn_mfma_f32_16x16x32_fp8_fp8(
                        a4[ti][kh], b4[tj][kh], acc[ti][tj], 0, 0, 0);
        __syncthreads();   // drains prefetch (landed during compute) + buf reuse
    }

    // Epilogue. acc holds log2(e)*score; E = exp2(acc).
    // C/D layout per 16x16 tile: col = lane&15, row = quad*4 + reg.
    float colp[4] = {0.f, 0.f, 0.f, 0.f};
    #pragma unroll
    for (int ti = 0; ti < 4; ++ti) {
        #pragma unroll
        for (int r = 0; r < 4; ++r) {
            float e0 = EXP2(acc[ti][0][r]);
            float e1 = EXP2(acc[ti][1][r]);
            float e2 = EXP2(acc[ti][2][r]);
            float e3 = EXP2(acc[ti][3][r]);
            if (diag) { colp[0] += e0; colp[1] += e1; colp[2] += e2; colp[3] += e3; }
            float rp = rowsum16((e0 + e1) + (e2 + e3));   // DPP, no LDS
            if (lrow == 15)
                ls_row2[wn][wm * 64 + ti * 16 + quad * 4 + r] = rp;
        }
    }
    if (diag) {
        #pragma unroll
        for (int tj = 0; tj < 4; ++tj) {
            float q = colp[tj];
            q += __shfl_xor(q, 16);
            q += __shfl_xor(q, 32);
            if (lane < 16)
                ls_col2[wm][wn * 64 + tj * 16 + lane] = q;
        }
    }
    __syncthreads();
    if (tid < 128) {
        const float rs = ls_row2[0][tid] + ls_row2[1][tid];
        const int rowg = tileM * 128 + tid;           // = i*T + q
        atomicAdd(&total[rowg], rs);
        if (diag) atomicAdd(&selfp[rowg], rs);
    } else if (diag) {
        const int t2 = tid - 128;
        atomicAdd(&ap[tileN * 128 + t2], ls_col2[0][t2] + ls_col2[1][t2]);
    }
}

// ---------------- fallback main (round-1 kernel, fp32 staging) ---------------
__global__ __launch_bounds__(256) void infonce_main_slow(
    const float* __restrict__ feat, const float* __restrict__ feat_aug,
    float* __restrict__ total, float* __restrict__ selfp, float* __restrict__ ap)
{
    __shared__ __align__(16) unsigned short As[128][72];
    __shared__ __align__(16) unsigned short Bs[128][72];
    __shared__ float ls_row[128];
    __shared__ float ls_col[128];

    const int tid  = threadIdx.x;
    const int lane = tid & 63;
    const int w    = tid >> 6;
    const int wm   = w >> 1;
    const int wn   = w & 1;
    const int lrow = lane & 15;
    const int quad = lane >> 4;

    const int tileM = blockIdx.x & 15;
    const int tileN = blockIdx.x >> 4;
    const int v     = blockIdx.y;
    const bool diag = (tileM >> 1) == (tileN >> 1);

    if (tid < 128) ls_row[tid] = 0.0f;
    else           ls_col[tid - 128] = 0.0f;

    const float* aBase = feat     + (size_t)v * 256;
    const float* bBase = feat_aug + (size_t)v * 256;

    f32x4 acc[4][4];
    #pragma unroll
    for (int i = 0; i < 4; ++i)
        #pragma unroll
        for (int j = 0; j < 4; ++j)
            acc[i][j] = (f32x4){0.f, 0.f, 0.f, 0.f};

    const int srow = tid >> 4;
    const int scol = (tid & 15) * 4;

    for (int s = 0; s < 4; ++s) {
        const int k0 = s * 64;
        if (s) __syncthreads();
        #pragma unroll
        for (int it = 0; it < 8; ++it) {
            const int row = it * 16 + srow;
            const float4 a4 = *(const float4*)(aBase + (size_t)(tileM * 128 + row) * 8192 + k0 + scol);
            const float4 b4 = *(const float4*)(bBase + (size_t)(tileN * 128 + row) * 8192 + k0 + scol);
            uint2 wa, wb;
            wa.x = (unsigned)f2bf(a4.x) | ((unsigned)f2bf(a4.y) << 16);
            wa.y = (unsigned)f2bf(a4.z) | ((unsigned)f2bf(a4.w) << 16);
            wb.x = (unsigned)f2bf(b4.x) | ((unsigned)f2bf(b4.y) << 16);
            wb.y = (unsigned)f2bf(b4.z) | ((unsigned)f2bf(b4.w) << 16);
            *(uint2*)&As[row][scol] = wa;
            *(uint2*)&Bs[row][scol] = wb;
        }
        __syncthreads();
        #pragma unroll
        for (int kk = 0; kk < 64; kk += 32) {
            bf16x8 af[4], bfr[4];
            #pragma unroll
            for (int t = 0; t < 4; ++t) {
                af[t]  = *(const bf16x8*)&As[wm * 64 + t * 16 + lrow][kk + quad * 8];
                bfr[t] = *(const bf16x8*)&Bs[wn * 64 + t * 16 + lrow][kk + quad * 8];
            }
            #pragma unroll
            for (int ti = 0; ti < 4; ++ti)
                #pragma unroll
                for (int tj = 0; tj < 4; ++tj)
                    acc[ti][tj] = __builtin_amdgcn_mfma_f32_16x16x32_bf16(
                        af[ti], bfr[tj], acc[ti][tj], 0, 0, 0);
        }
    }

    float colp[4] = {0.f, 0.f, 0.f, 0.f};
    #pragma unroll
    for (int ti = 0; ti < 4; ++ti) {
        #pragma unroll
        for (int r = 0; r < 4; ++r) {
            float e0 = __expf(acc[ti][0][r]);
            float e1 = __expf(acc[ti][1][r]);
            float e2 = __expf(acc[ti][2][r]);
            float e3 = __expf(acc[ti][3][r]);
            colp[0] += e0; colp[1] += e1; colp[2] += e2; colp[3] += e3;
            float rp = (e0 + e1) + (e2 + e3);
            rp += __shfl_xor(rp, 1);
            rp += __shfl_xor(rp, 2);
            rp += __shfl_xor(rp, 4);
            rp += __shfl_xor(rp, 8);
            if (lrow == 0)
                atomicAdd(&ls_row[wm * 64 + ti * 16 + quad * 4 + r], rp);
        }
    }
    if (diag) {
        #pragma unroll
        for (int tj = 0; tj < 4; ++tj) {
            float q = colp[tj];
            q += __shfl_xor(q, 16);
            q += __shfl_xor(q, 32);
            if (lane < 16)
                atomicAdd(&ls_col[wn * 64 + tj * 16 + lane], q);
        }
    }
    __syncthreads();
    if (tid < 128) {
        const float rs = ls_row[tid];
        const int rowg = tileM * 128 + tid;
        atomicAdd(&total[rowg], rs);
        if (diag) atomicAdd(&selfp[rowg], rs);
    } else if (diag) {
        const int t2 = tid - 128;
        atomicAdd(&ap[tileN * 128 + t2], ls_col[t2]);
    }
}

__global__ __launch_bounds__(256) void infonce_finalize(
    const float* __restrict__ total, const float* __restrict__ selfp,
    const float* __restrict__ ap, float* __restrict__ out)
{
    __shared__ float red[4];
    const int tid = threadIdx.x;
    float s = 0.f;
    for (int e = tid; e < 2048; e += 256) {
        const float an = total[e] - selfp[e];
        s += logf(an / ap[e]);
    }
    #pragma unroll
    for (int m = 32; m >= 1; m >>= 1) s += __shfl_xor(s, m);
    if ((tid & 63) == 0) red[tid >> 6] = s;
    __syncthreads();
    if (tid == 0) out[0] = (red[0] + red[1] + red[2] + red[3]) * (1.0f / 256.0f);
}

extern "C" void kernel_launch(void* const* d_in, const int* in_sizes, int n_in,
                              void* d_out, int out_size, void* d_ws, size_t ws_size,
                              hipStream_t stream) {
    const float* feat     = (const float*)d_in[0];
    const float* feat_aug = (const float*)d_in[1];
    float* total = (float*)d_ws;
    float* selfp = total + 2048;
    float* ap    = selfp + 2048;

    const size_t packBytes = (size_t)2048 * 8192;                  // per tensor, fp8
    const size_t need = 32768 + 2 * packBytes;
    if (ws_size >= need) {
        unsigned char* pA = (unsigned char*)d_ws + 32768;
        unsigned char* pB = pA + packBytes;
        infonce_repack_fp8<<<dim3(2048, 2), 256, 0, stream>>>(feat, feat_aug, pA, pB, total);
        infonce_main_fp8<<<dim3(256, 32), 256, 0, stream>>>(pA, pB, total, selfp, ap);
    } else {
        (void)hipMemsetAsync(d_ws, 0, 3 * 2048 * sizeof(float), stream);
        infonce_main_slow<<<dim3(256, 32), 256, 0, stream>>>(feat, feat_aug, total, selfp, ap);
    }
    infonce_finalize<<<1, 256, 0, stream>>>(total, selfp, ap, (float*)d_out);
}

// Round 7
// 200.096 us; speedup vs baseline: 1.3071x; 1.0373x over previous
//
#include <hip/hip_runtime.h>
#include <hip/hip_bf16.h>

// Problem: B=8, T=256, V=32, D=256.
// Per-v GEMM: M=N=2048 (rows = i*T+q / j*T+k), K=256, then exp + 3 reductions.
// feature[B,T,V,D]: element (row, v, d) at feat[(row*32 + v)*256 + d].
// Fast path: fp8 e4m3 repack (plain layout, A prescaled by log2(e)); main GEMM
// uses MX-scaled mfma_scale_f32_16x16x128_f8f6f4 with unit scales (2x the
// plain-fp8 rate), single-shot K=256 staging into 64 KB LDS with a 16B-group
// XOR swizzle (pg = lg ^ (row&15)) for bank-floor b128 reads.

typedef __attribute__((ext_vector_type(4))) float f32x4;
typedef __attribute__((ext_vector_type(4))) int   i32x4;
typedef __attribute__((ext_vector_type(8))) int   i32x8;
typedef __attribute__((ext_vector_type(8))) __bf16 bf16x8;   // fallback path

#if __has_builtin(__builtin_amdgcn_exp2f)
#define EXP2(x) __builtin_amdgcn_exp2f(x)
#else
#define EXP2(x) exp2f(x)
#endif

__device__ __forceinline__ unsigned short f2bf(float f) {
    unsigned u = __builtin_bit_cast(unsigned, f);
    u += 0x7FFFu + ((u >> 16) & 1u);   // RNE (no NaNs in data)
    return (unsigned short)(u >> 16);
}

template <bool HI>
__device__ __forceinline__ unsigned cvt2fp8(float a, float b, unsigned old) {
    return __builtin_amdgcn_cvt_pk_fp8_f32(a, b, old, HI);
}
__device__ __forceinline__ unsigned pack4fp8(float x, float y, float z, float w) {
    return cvt2fp8<true>(z, w, cvt2fp8<false>(x, y, 0u));
}

__device__ __forceinline__ void async16(const void* g, void* l) {
    __builtin_amdgcn_global_load_lds(
        (const __attribute__((address_space(1))) unsigned int*)g,
        (__attribute__((address_space(3))) unsigned int*)l,
        16, 0, 0);
}

__device__ __forceinline__ i32x8 cat8(i32x4 lo, i32x4 hi) {
    i32x8 r;
    r[0] = lo[0]; r[1] = lo[1]; r[2] = lo[2]; r[3] = lo[3];
    r[4] = hi[0]; r[5] = hi[1]; r[6] = hi[2]; r[7] = hi[3];
    return r;
}

// DPP row-sum over 16-lane rows; full sum lands in lane 15 of each row.
template <int CTRL>
__device__ __forceinline__ float dpp_add(float x) {
    int y = __builtin_amdgcn_update_dpp(0, __builtin_bit_cast(int, x),
                                        CTRL, 0xf, 0xf, true);
    return x + __builtin_bit_cast(float, y);
}
__device__ __forceinline__ float rowsum16(float x) {
    x = dpp_add<0x111>(x);   // row_shr:1
    x = dpp_add<0x112>(x);   // row_shr:2
    x = dpp_add<0x114>(x);   // row_shr:4
    x = dpp_add<0x118>(x);   // row_shr:8
    return x;
}

// ------------- repack: streaming fp32 -> fp8 e4m3 (plain layout) -------------
// grid (2048, 2): one row (8192 floats -> 8192 bytes) per block; y = tensor.
// Block (0,0) also zeroes the 3*2048 counter floats (replaces memset dispatch).
__global__ __launch_bounds__(256) void infonce_repack_fp8(
    const float* __restrict__ feat, const float* __restrict__ feat_aug,
    unsigned char* __restrict__ pA, unsigned char* __restrict__ pB,
    float* __restrict__ counters)
{
    const int row = blockIdx.x;
    const int tid = threadIdx.x;
    if (blockIdx.x == 0 && blockIdx.y == 0) {
        #pragma unroll
        for (int k = 0; k < 24; ++k) counters[k * 256 + tid] = 0.f;
    }
    const bool isA = (blockIdx.y == 0);
    const float sc = isA ? 1.4426950408889634f : 1.0f;
    const float* src = (isA ? feat : feat_aug) + (size_t)row * 8192;
    unsigned char* dst = (isA ? pA : pB) + (size_t)row * 8192;
    #pragma unroll
    for (int it = 0; it < 2; ++it) {
        const int base = it * 4096 + tid * 16;
        const float4 f0 = *(const float4*)(src + base);
        const float4 f1 = *(const float4*)(src + base + 4);
        const float4 f2 = *(const float4*)(src + base + 8);
        const float4 f3 = *(const float4*)(src + base + 12);
        uint4 p;
        p.x = pack4fp8(f0.x*sc, f0.y*sc, f0.z*sc, f0.w*sc);
        p.y = pack4fp8(f1.x*sc, f1.y*sc, f1.z*sc, f1.w*sc);
        p.z = pack4fp8(f2.x*sc, f2.y*sc, f2.z*sc, f2.w*sc);
        p.w = pack4fp8(f3.x*sc, f3.y*sc, f3.z*sc, f3.w*sc);
        *(uint4*)(dst + base) = p;
    }
}

// ----- main: per-v 2048x2048x256 MX-fp8 GEMM (K=128 x2) + exp + reductions ---
// LDS per operand: [128 rows][16 groups of 16 B]; physical group
// pg = lg ^ (row & 15). Single-shot: whole K=256 staged once.
__global__ __launch_bounds__(256, 2) void infonce_main_mx(
    const unsigned char* __restrict__ pA, const unsigned char* __restrict__ pB,
    float* __restrict__ total, float* __restrict__ selfp, float* __restrict__ ap)
{
    __shared__ __align__(16) unsigned char As[128 * 256];
    __shared__ __align__(16) unsigned char Bs[128 * 256];
    // reduction scratch aliases As after the post-MFMA barrier
    float (*ls_row2)[128] = (float (*)[128])(void*)As;
    float (*ls_col2)[128] = (float (*)[128])(void*)(As + 1024);

    const int tid  = threadIdx.x;
    const int lane = tid & 63;
    const int w    = tid >> 6;        // wave 0..3
    const int wm   = w >> 1;
    const int wn   = w & 1;
    const int lrow = lane & 15;
    const int quad = lane >> 4;

    const int tileM = blockIdx.x & 15;
    const int tileN = blockIdx.x >> 4;
    const int v     = blockIdx.y;
    const bool diag = (tileM >> 1) == (tileN >> 1);   // i == j (256-row batches)

    // ---- staging: wave w covers rows [w*32, w*32+32); issue i = 4 rows ----
    // lane l of issue i -> local row i*4 + (l>>4), physical group l&15, which
    // holds logical group (l&15) ^ ((i*4 + (l>>4)) & 15).
    const size_t vOff = (size_t)v * 256;
    const size_t rowM = (size_t)(tileM * 128 + w * 32 + quad) * 8192 + vOff;
    const size_t rowN = (size_t)(tileN * 128 + w * 32 + quad) * 8192 + vOff;
    #pragma unroll
    for (int i = 0; i < 8; ++i) {
        const int lg = (lrow ^ ((i * 4 + quad) & 15)) << 4;
        async16(pA + rowM + (size_t)i * 4 * 8192 + lg, &As[(w * 32 + i * 4) * 256]);
        async16(pB + rowN + (size_t)i * 4 * 8192 + lg, &Bs[(w * 32 + i * 4) * 256]);
    }

    f32x4 acc[4][4];
    #pragma unroll
    for (int i = 0; i < 4; ++i)
        #pragma unroll
        for (int j = 0; j < 4; ++j)
            acc[i][j] = (f32x4){0.f, 0.f, 0.f, 0.f};

    __syncthreads();   // drains vmcnt: all 64 KB staged

    // ---- MFMA: 2 K-halves of 128; frag k = h*128 + quad*32 + [0..31] -------
    #pragma unroll
    for (int h = 0; h < 2; ++h) {
        const int g0 = ((h * 8 + quad * 2) ^ lrow) * 16;   // pg of lg, lg^1 = +-16
        const int g1 = g0 ^ 16;
        i32x8 af[4], bf[4];
        #pragma unroll
        for (int t = 0; t < 4; ++t) {
            const int rA = (wm * 64 + t * 16 + lrow) * 256;
            const int rB = (wn * 64 + t * 16 + lrow) * 256;
            af[t] = cat8(*(const i32x4*)&As[rA + g0], *(const i32x4*)&As[rA + g1]);
            bf[t] = cat8(*(const i32x4*)&Bs[rB + g0], *(const i32x4*)&Bs[rB + g1]);
        }
        #pragma unroll
        for (int ti = 0; ti < 4; ++ti)
            #pragma unroll
            for (int tj = 0; tj < 4; ++tj)
                acc[ti][tj] = __builtin_amdgcn_mfma_scale_f32_16x16x128_f8f6f4(
                    af[ti], bf[tj], acc[ti][tj],
                    0, 0,          // cbsz = fp8 e4m3, blgp = fp8 e4m3
                    0, 127,        // scale A: opsel 0, E8M0 127 = 1.0
                    0, 127);       // scale B: opsel 0, E8M0 127 = 1.0
    }

    __syncthreads();   // all LDS tile reads done -> safe to reuse As as scratch

    // Epilogue. acc holds log2(e)*score; E = exp2(acc).
    // C/D layout per 16x16 tile: col = lane&15, row = quad*4 + reg.
    float colp[4] = {0.f, 0.f, 0.f, 0.f};
    #pragma unroll
    for (int ti = 0; ti < 4; ++ti) {
        #pragma unroll
        for (int r = 0; r < 4; ++r) {
            float e0 = EXP2(acc[ti][0][r]);
            float e1 = EXP2(acc[ti][1][r]);
            float e2 = EXP2(acc[ti][2][r]);
            float e3 = EXP2(acc[ti][3][r]);
            if (diag) { colp[0] += e0; colp[1] += e1; colp[2] += e2; colp[3] += e3; }
            float rp = rowsum16((e0 + e1) + (e2 + e3));   // DPP, no LDS
            if (lrow == 15)
                ls_row2[wn][wm * 64 + ti * 16 + quad * 4 + r] = rp;
        }
    }
    if (diag) {
        #pragma unroll
        for (int tj = 0; tj < 4; ++tj) {
            float q = colp[tj];
            q += __shfl_xor(q, 16);
            q += __shfl_xor(q, 32);
            if (lane < 16)
                ls_col2[wm][wn * 64 + tj * 16 + lane] = q;
        }
    }
    __syncthreads();
    if (tid < 128) {
        const float rs = ls_row2[0][tid] + ls_row2[1][tid];
        const int rowg = tileM * 128 + tid;           // = i*T + q
        atomicAdd(&total[rowg], rs);
        if (diag) atomicAdd(&selfp[rowg], rs);
    } else if (diag) {
        const int t2 = tid - 128;
        atomicAdd(&ap[tileN * 128 + t2], ls_col2[0][t2] + ls_col2[1][t2]);
    }
}

// ---------------- fallback main (round-1 kernel, fp32 staging) ---------------
__global__ __launch_bounds__(256) void infonce_main_slow(
    const float* __restrict__ feat, const float* __restrict__ feat_aug,
    float* __restrict__ total, float* __restrict__ selfp, float* __restrict__ ap)
{
    __shared__ __align__(16) unsigned short As[128][72];
    __shared__ __align__(16) unsigned short Bs[128][72];
    __shared__ float ls_row[128];
    __shared__ float ls_col[128];

    const int tid  = threadIdx.x;
    const int lane = tid & 63;
    const int w    = tid >> 6;
    const int wm   = w >> 1;
    const int wn   = w & 1;
    const int lrow = lane & 15;
    const int quad = lane >> 4;

    const int tileM = blockIdx.x & 15;
    const int tileN = blockIdx.x >> 4;
    const int v     = blockIdx.y;
    const bool diag = (tileM >> 1) == (tileN >> 1);

    if (tid < 128) ls_row[tid] = 0.0f;
    else           ls_col[tid - 128] = 0.0f;

    const float* aBase = feat     + (size_t)v * 256;
    const float* bBase = feat_aug + (size_t)v * 256;

    f32x4 acc[4][4];
    #pragma unroll
    for (int i = 0; i < 4; ++i)
        #pragma unroll
        for (int j = 0; j < 4; ++j)
            acc[i][j] = (f32x4){0.f, 0.f, 0.f, 0.f};

    const int srow = tid >> 4;
    const int scol = (tid & 15) * 4;

    for (int s = 0; s < 4; ++s) {
        const int k0 = s * 64;
        if (s) __syncthreads();
        #pragma unroll
        for (int it = 0; it < 8; ++it) {
            const int row = it * 16 + srow;
            const float4 a4 = *(const float4*)(aBase + (size_t)(tileM * 128 + row) * 8192 + k0 + scol);
            const float4 b4 = *(const float4*)(bBase + (size_t)(tileN * 128 + row) * 8192 + k0 + scol);
            uint2 wa, wb;
            wa.x = (unsigned)f2bf(a4.x) | ((unsigned)f2bf(a4.y) << 16);
            wa.y = (unsigned)f2bf(a4.z) | ((unsigned)f2bf(a4.w) << 16);
            wb.x = (unsigned)f2bf(b4.x) | ((unsigned)f2bf(b4.y) << 16);
            wb.y = (unsigned)f2bf(b4.z) | ((unsigned)f2bf(b4.w) << 16);
            *(uint2*)&As[row][scol] = wa;
            *(uint2*)&Bs[row][scol] = wb;
        }
        __syncthreads();
        #pragma unroll
        for (int kk = 0; kk < 64; kk += 32) {
            bf16x8 af[4], bfr[4];
            #pragma unroll
            for (int t = 0; t < 4; ++t) {
                af[t]  = *(const bf16x8*)&As[wm * 64 + t * 16 + lrow][kk + quad * 8];
                bfr[t] = *(const bf16x8*)&Bs[wn * 64 + t * 16 + lrow][kk + quad * 8];
            }
            #pragma unroll
            for (int ti = 0; ti < 4; ++ti)
                #pragma unroll
                for (int tj = 0; tj < 4; ++tj)
                    acc[ti][tj] = __builtin_amdgcn_mfma_f32_16x16x32_bf16(
                        af[ti], bfr[tj], acc[ti][tj], 0, 0, 0);
        }
    }

    float colp[4] = {0.f, 0.f, 0.f, 0.f};
    #pragma unroll
    for (int ti = 0; ti < 4; ++ti) {
        #pragma unroll
        for (int r = 0; r < 4; ++r) {
            float e0 = __expf(acc[ti][0][r]);
            float e1 = __expf(acc[ti][1][r]);
            float e2 = __expf(acc[ti][2][r]);
            float e3 = __expf(acc[ti][3][r]);
            colp[0] += e0; colp[1] += e1; colp[2] += e2; colp[3] += e3;
            float rp = (e0 + e1) + (e2 + e3);
            rp += __shfl_xor(rp, 1);
            rp += __shfl_xor(rp, 2);
            rp += __shfl_xor(rp, 4);
            rp += __shfl_xor(rp, 8);
            if (lrow == 0)
                atomicAdd(&ls_row[wm * 64 + ti * 16 + quad * 4 + r], rp);
        }
    }
    if (diag) {
        #pragma unroll
        for (int tj = 0; tj < 4; ++tj) {
            float q = colp[tj];
            q += __shfl_xor(q, 16);
            q += __shfl_xor(q, 32);
            if (lane < 16)
                atomicAdd(&ls_col[wn * 64 + tj * 16 + lane], q);
        }
    }
    __syncthreads();
    if (tid < 128) {
        const float rs = ls_row[tid];
        const int rowg = tileM * 128 + tid;
        atomicAdd(&total[rowg], rs);
        if (diag) atomicAdd(&selfp[rowg], rs);
    } else if (diag) {
        const int t2 = tid - 128;
        atomicAdd(&ap[tileN * 128 + t2], ls_col[t2]);
    }
}

__global__ __launch_bounds__(256) void infonce_finalize(
    const float* __restrict__ total, const float* __restrict__ selfp,
    const float* __restrict__ ap, float* __restrict__ out)
{
    __shared__ float red[4];
    const int tid = threadIdx.x;
    float s = 0.f;
    for (int e = tid; e < 2048; e += 256) {
        const float an = total[e] - selfp[e];
        s += logf(an / ap[e]);
    }
    #pragma unroll
    for (int m = 32; m >= 1; m >>= 1) s += __shfl_xor(s, m);
    if ((tid & 63) == 0) red[tid >> 6] = s;
    __syncthreads();
    if (tid == 0) out[0] = (red[0] + red[1] + red[2] + red[3]) * (1.0f / 256.0f);
}

extern "C" void kernel_launch(void* const* d_in, const int* in_sizes, int n_in,
                              void* d_out, int out_size, void* d_ws, size_t ws_size,
                              hipStream_t stream) {
    const float* feat     = (const float*)d_in[0];
    const float* feat_aug = (const float*)d_in[1];
    float* total = (float*)d_ws;
    float* selfp = total + 2048;
    float* ap    = selfp + 2048;

    const size_t packBytes = (size_t)2048 * 8192;                  // per tensor, fp8
    const size_t need = 32768 + 2 * packBytes;
    if (ws_size >= need) {
        unsigned char* pA = (unsigned char*)d_ws + 32768;
        unsigned char* pB = pA + packBytes;
        infonce_repack_fp8<<<dim3(2048, 2), 256, 0, stream>>>(feat, feat_aug, pA, pB, total);
        infonce_main_mx<<<dim3(256, 32), 256, 0, stream>>>(pA, pB, total, selfp, ap);
    } else {
        (void)hipMemsetAsync(d_ws, 0, 3 * 2048 * sizeof(float), stream);
        infonce_main_slow<<<dim3(256, 32), 256, 0, stream>>>(feat, feat_aug, total, selfp, ap);
    }
    infonce_finalize<<<1, 256, 0, stream>>>(total, selfp, ap, (float*)d_out);
}

// Round 8
// 193.444 us; speedup vs baseline: 1.3521x; 1.0344x over previous
//
#include <hip/hip_runtime.h>
#include <hip/hip_bf16.h>

// Problem: B=8, T=256, V=32, D=256.
// Per-v GEMM: M=N=2048 (rows = i*T+q / j*T+k), K=256, then exp + 3 reductions.
// feature[B,T,V,D]: element (row, v, d) at feat[(row*32 + v)*256 + d].
// Fast path: fp8 e4m3 repack (A prescaled by log2(e)); main kernel is an
// N-sweep: block=(tileM,v) stages its 128x256B A-tile once (frags hoisted to
// registers), then sweeps N in 32 double-buffered 64-row B half-tiles using
// MX-scaled mfma_scale_f32_16x16x128_f8f6f4 (unit scales). Row/self sums
// accumulate in registers across the sweep; DPP rowsum + one atomic at end.

typedef __attribute__((ext_vector_type(4))) float f32x4;
typedef __attribute__((ext_vector_type(4))) int   i32x4;
typedef __attribute__((ext_vector_type(8))) int   i32x8;
typedef __attribute__((ext_vector_type(8))) __bf16 bf16x8;   // fallback path

#if __has_builtin(__builtin_amdgcn_exp2f)
#define EXP2(x) __builtin_amdgcn_exp2f(x)
#else
#define EXP2(x) exp2f(x)
#endif

__device__ __forceinline__ unsigned short f2bf(float f) {
    unsigned u = __builtin_bit_cast(unsigned, f);
    u += 0x7FFFu + ((u >> 16) & 1u);   // RNE (no NaNs in data)
    return (unsigned short)(u >> 16);
}

template <bool HI>
__device__ __forceinline__ unsigned cvt2fp8(float a, float b, unsigned old) {
    return __builtin_amdgcn_cvt_pk_fp8_f32(a, b, old, HI);
}
__device__ __forceinline__ unsigned pack4fp8(float x, float y, float z, float w) {
    return cvt2fp8<true>(z, w, cvt2fp8<false>(x, y, 0u));
}

__device__ __forceinline__ void async16(const void* g, void* l) {
    __builtin_amdgcn_global_load_lds(
        (const __attribute__((address_space(1))) unsigned int*)g,
        (__attribute__((address_space(3))) unsigned int*)l,
        16, 0, 0);
}

__device__ __forceinline__ i32x8 cat8(i32x4 lo, i32x4 hi) {
    i32x8 r;
    r[0] = lo[0]; r[1] = lo[1]; r[2] = lo[2]; r[3] = lo[3];
    r[4] = hi[0]; r[5] = hi[1]; r[6] = hi[2]; r[7] = hi[3];
    return r;
}

// DPP row-sum over 16-lane rows; full sum lands in lane 15 of each row.
template <int CTRL>
__device__ __forceinline__ float dpp_add(float x) {
    int y = __builtin_amdgcn_update_dpp(0, __builtin_bit_cast(int, x),
                                        CTRL, 0xf, 0xf, true);
    return x + __builtin_bit_cast(float, y);
}
__device__ __forceinline__ float rowsum16(float x) {
    x = dpp_add<0x111>(x);   // row_shr:1
    x = dpp_add<0x112>(x);   // row_shr:2
    x = dpp_add<0x114>(x);   // row_shr:4
    x = dpp_add<0x118>(x);   // row_shr:8
    return x;
}

// ------------- repack: streaming fp32 -> fp8 e4m3 (plain layout) -------------
// grid (2048, 2): one row (8192 floats -> 8192 bytes) per block; y = tensor.
// Block (0,0) also zeroes the 3*2048 counter floats (replaces memset dispatch).
__global__ __launch_bounds__(256) void infonce_repack_fp8(
    const float* __restrict__ feat, const float* __restrict__ feat_aug,
    unsigned char* __restrict__ pA, unsigned char* __restrict__ pB,
    float* __restrict__ counters)
{
    const int row = blockIdx.x;
    const int tid = threadIdx.x;
    if (blockIdx.x == 0 && blockIdx.y == 0) {
        #pragma unroll
        for (int k = 0; k < 24; ++k) counters[k * 256 + tid] = 0.f;
    }
    const bool isA = (blockIdx.y == 0);
    const float sc = isA ? 1.4426950408889634f : 1.0f;
    const float* src = (isA ? feat : feat_aug) + (size_t)row * 8192;
    unsigned char* dst = (isA ? pA : pB) + (size_t)row * 8192;
    #pragma unroll
    for (int it = 0; it < 2; ++it) {
        const int base = it * 4096 + tid * 16;
        const float4 f0 = *(const float4*)(src + base);
        const float4 f1 = *(const float4*)(src + base + 4);
        const float4 f2 = *(const float4*)(src + base + 8);
        const float4 f3 = *(const float4*)(src + base + 12);
        uint4 p;
        p.x = pack4fp8(f0.x*sc, f0.y*sc, f0.z*sc, f0.w*sc);
        p.y = pack4fp8(f1.x*sc, f1.y*sc, f1.z*sc, f1.w*sc);
        p.z = pack4fp8(f2.x*sc, f2.y*sc, f2.z*sc, f2.w*sc);
        p.w = pack4fp8(f3.x*sc, f3.y*sc, f3.z*sc, f3.w*sc);
        *(uint4*)(dst + base) = p;
    }
}

// ----- main: N-sweep MX-fp8 GEMM + exp + reductions ------------------------
// block = (tileM 0..15, v 0..31). A: [128 rows][16 groups x 16B],
// pg = lg ^ (row&15). B: 2 x [64 rows][256 B], same swizzle. 64 KB LDS total.
__global__ __launch_bounds__(256, 2) void infonce_main_nl(
    const unsigned char* __restrict__ pA, const unsigned char* __restrict__ pB,
    float* __restrict__ total, float* __restrict__ selfp, float* __restrict__ ap)
{
    __shared__ __align__(16) unsigned char As[128 * 256];
    __shared__ __align__(16) unsigned char Bs[2][64 * 256];
    // scratch aliases As after the final loop barrier (A frags live in regs)
    float (*ls_row2)[128]  = (float (*)[128])(void*)As;
    float (*ls_self2)[128] = (float (*)[128])(void*)(As + 1024);

    const int tid  = threadIdx.x;
    const int lane = tid & 63;
    const int w    = tid >> 6;        // wave 0..3
    const int wm   = w >> 1;          // A rows half
    const int wn   = w & 1;           // B cols half (within 64-col tile)
    const int lrow = lane & 15;
    const int quad = lane >> 4;

    const int tileM = blockIdx.x;     // 0..15
    const int v     = blockIdx.y;     // 0..31
    const int nD0   = (tileM >> 1) * 4;   // first diagonal n-iter

    const size_t vOff = (size_t)v * 256;

    // ---- stage A (128 rows x 256 B), swizzled, once ----
    {
        const size_t rowM = (size_t)(tileM * 128 + w * 32 + quad) * 8192 + vOff;
        #pragma unroll
        for (int i = 0; i < 8; ++i) {
            const int lg = (lrow ^ ((i * 4 + quad) & 15)) << 4;
            async16(pA + rowM + (size_t)i * 4 * 8192 + lg, &As[(w * 32 + i * 4) * 256]);
        }
    }
    // ---- stage B tile 0 ----
    const size_t rowNbase = (size_t)(w * 16 + quad) * 8192 + vOff;
    #pragma unroll
    for (int i = 0; i < 4; ++i) {
        const int lg = (lrow ^ ((i * 4 + quad) & 15)) << 4;
        async16(pB + rowNbase + (size_t)i * 4 * 8192 + lg,
                &Bs[0][(w * 16 + i * 4) * 256]);
    }
    __syncthreads();

    // ---- hoist A fragments to registers (LDS read once) ----
    i32x8 af[2][4];   // [k-half][m-tile]
    #pragma unroll
    for (int h = 0; h < 2; ++h)
        #pragma unroll
        for (int t = 0; t < 4; ++t) {
            const int rA = (wm * 64 + t * 16 + lrow) * 256;
            const int g0 = ((h * 8 + quad * 2) ^ lrow) * 16;
            af[h][t] = cat8(*(const i32x4*)&As[rA + g0],
                            *(const i32x4*)&As[rA + (g0 ^ 16)]);
        }

    float rowp[4][4];   // row partials, all n
    float selfr[4][4];  // row partials, diagonal n only
    #pragma unroll
    for (int t = 0; t < 4; ++t)
        #pragma unroll
        for (int r = 0; r < 4; ++r) { rowp[t][r] = 0.f; selfr[t][r] = 0.f; }

    for (int n = 0; n < 32; ++n) {
        const int b = n & 1;
        if (n < 31) {   // prefetch next B half-tile
            const unsigned char* src = pB + rowNbase + (size_t)(n + 1) * 64 * 8192;
            #pragma unroll
            for (int i = 0; i < 4; ++i) {
                const int lg = (lrow ^ ((i * 4 + quad) & 15)) << 4;
                async16(src + (size_t)i * 4 * 8192 + lg,
                        &Bs[b ^ 1][(w * 16 + i * 4) * 256]);
            }
        }
        f32x4 acc[4][2];
        #pragma unroll
        for (int t = 0; t < 4; ++t)
            #pragma unroll
            for (int tj = 0; tj < 2; ++tj)
                acc[t][tj] = (f32x4){0.f, 0.f, 0.f, 0.f};
        #pragma unroll
        for (int h = 0; h < 2; ++h) {
            i32x8 bf[2];
            #pragma unroll
            for (int tj = 0; tj < 2; ++tj) {
                const int rB = (wn * 32 + tj * 16 + lrow) * 256;
                const int g0 = ((h * 8 + quad * 2) ^ lrow) * 16;
                bf[tj] = cat8(*(const i32x4*)&Bs[b][rB + g0],
                              *(const i32x4*)&Bs[b][rB + (g0 ^ 16)]);
            }
            #pragma unroll
            for (int ti = 0; ti < 4; ++ti)
                #pragma unroll
                for (int tj = 0; tj < 2; ++tj)
                    acc[ti][tj] = __builtin_amdgcn_mfma_scale_f32_16x16x128_f8f6f4(
                        af[h][ti], bf[tj], acc[ti][tj],
                        0, 0, 0, 127, 0, 127);   // fp8/fp8, unit E8M0 scales
        }
        // epilogue-accumulate: E = exp2(acc) (A prescaled by log2 e)
        const bool diagIter = (n >= nD0) && (n < nD0 + 4);
        float colp0 = 0.f, colp1 = 0.f;
        #pragma unroll
        for (int t = 0; t < 4; ++t)
            #pragma unroll
            for (int r = 0; r < 4; ++r) {
                float e0 = EXP2(acc[t][0][r]);
                float e1 = EXP2(acc[t][1][r]);
                rowp[t][r] += e0 + e1;
                if (diagIter) { selfr[t][r] += e0 + e1; colp0 += e0; colp1 += e1; }
            }
        if (diagIter) {   // col sums -> ap (wave-uniform branch, 4 of 32 iters)
            float q0 = colp0, q1 = colp1;
            q0 += __shfl_xor(q0, 16); q0 += __shfl_xor(q0, 32);
            q1 += __shfl_xor(q1, 16); q1 += __shfl_xor(q1, 32);
            if (lane < 16) {
                atomicAdd(&ap[n * 64 + wn * 32 + lane], q0);
                atomicAdd(&ap[n * 64 + wn * 32 + 16 + lane], q1);
            }
        }
        __syncthreads();   // B[b] reads done + prefetch drained
    }

    // ---- final row reductions: DPP over the 16 cols held per lane-row ----
    #pragma unroll
    for (int t = 0; t < 4; ++t)
        #pragma unroll
        for (int r = 0; r < 4; ++r) {
            float rs = rowsum16(rowp[t][r]);
            float ss = rowsum16(selfr[t][r]);
            if (lrow == 15) {
                const int idx = wm * 64 + t * 16 + quad * 4 + r;
                ls_row2[wn][idx]  = rs;
                ls_self2[wn][idx] = ss;
            }
        }
    __syncthreads();
    if (tid < 128) {
        atomicAdd(&total[tileM * 128 + tid], ls_row2[0][tid] + ls_row2[1][tid]);
    } else {
        const int t2 = tid - 128;
        atomicAdd(&selfp[tileM * 128 + t2], ls_self2[0][t2] + ls_self2[1][t2]);
    }
}

// ---------------- fallback main (round-1 kernel, fp32 staging) ---------------
__global__ __launch_bounds__(256) void infonce_main_slow(
    const float* __restrict__ feat, const float* __restrict__ feat_aug,
    float* __restrict__ total, float* __restrict__ selfp, float* __restrict__ ap)
{
    __shared__ __align__(16) unsigned short As[128][72];
    __shared__ __align__(16) unsigned short Bs[128][72];
    __shared__ float ls_row[128];
    __shared__ float ls_col[128];

    const int tid  = threadIdx.x;
    const int lane = tid & 63;
    const int w    = tid >> 6;
    const int wm   = w >> 1;
    const int wn   = w & 1;
    const int lrow = lane & 15;
    const int quad = lane >> 4;

    const int tileM = blockIdx.x & 15;
    const int tileN = blockIdx.x >> 4;
    const int v     = blockIdx.y;
    const bool diag = (tileM >> 1) == (tileN >> 1);

    if (tid < 128) ls_row[tid] = 0.0f;
    else           ls_col[tid - 128] = 0.0f;

    const float* aBase = feat     + (size_t)v * 256;
    const float* bBase = feat_aug + (size_t)v * 256;

    f32x4 acc[4][4];
    #pragma unroll
    for (int i = 0; i < 4; ++i)
        #pragma unroll
        for (int j = 0; j < 4; ++j)
            acc[i][j] = (f32x4){0.f, 0.f, 0.f, 0.f};

    const int srow = tid >> 4;
    const int scol = (tid & 15) * 4;

    for (int s = 0; s < 4; ++s) {
        const int k0 = s * 64;
        if (s) __syncthreads();
        #pragma unroll
        for (int it = 0; it < 8; ++it) {
            const int row = it * 16 + srow;
            const float4 a4 = *(const float4*)(aBase + (size_t)(tileM * 128 + row) * 8192 + k0 + scol);
            const float4 b4 = *(const float4*)(bBase + (size_t)(tileN * 128 + row) * 8192 + k0 + scol);
            uint2 wa, wb;
            wa.x = (unsigned)f2bf(a4.x) | ((unsigned)f2bf(a4.y) << 16);
            wa.y = (unsigned)f2bf(a4.z) | ((unsigned)f2bf(a4.w) << 16);
            wb.x = (unsigned)f2bf(b4.x) | ((unsigned)f2bf(b4.y) << 16);
            wb.y = (unsigned)f2bf(b4.z) | ((unsigned)f2bf(b4.w) << 16);
            *(uint2*)&As[row][scol] = wa;
            *(uint2*)&Bs[row][scol] = wb;
        }
        __syncthreads();
        #pragma unroll
        for (int kk = 0; kk < 64; kk += 32) {
            bf16x8 af[4], bfr[4];
            #pragma unroll
            for (int t = 0; t < 4; ++t) {
                af[t]  = *(const bf16x8*)&As[wm * 64 + t * 16 + lrow][kk + quad * 8];
                bfr[t] = *(const bf16x8*)&Bs[wn * 64 + t * 16 + lrow][kk + quad * 8];
            }
            #pragma unroll
            for (int ti = 0; ti < 4; ++ti)
                #pragma unroll
                for (int tj = 0; tj < 4; ++tj)
                    acc[ti][tj] = __builtin_amdgcn_mfma_f32_16x16x32_bf16(
                        af[ti], bfr[tj], acc[ti][tj], 0, 0, 0);
        }
    }

    float colp[4] = {0.f, 0.f, 0.f, 0.f};
    #pragma unroll
    for (int ti = 0; ti < 4; ++ti) {
        #pragma unroll
        for (int r = 0; r < 4; ++r) {
            float e0 = __expf(acc[ti][0][r]);
            float e1 = __expf(acc[ti][1][r]);
            float e2 = __expf(acc[ti][2][r]);
            float e3 = __expf(acc[ti][3][r]);
            colp[0] += e0; colp[1] += e1; colp[2] += e2; colp[3] += e3;
            float rp = (e0 + e1) + (e2 + e3);
            rp += __shfl_xor(rp, 1);
            rp += __shfl_xor(rp, 2);
            rp += __shfl_xor(rp, 4);
            rp += __shfl_xor(rp, 8);
            if (lrow == 0)
                atomicAdd(&ls_row[wm * 64 + ti * 16 + quad * 4 + r], rp);
        }
    }
    if (diag) {
        #pragma unroll
        for (int tj = 0; tj < 4; ++tj) {
            float q = colp[tj];
            q += __shfl_xor(q, 16);
            q += __shfl_xor(q, 32);
            if (lane < 16)
                atomicAdd(&ls_col[wn * 64 + tj * 16 + lane], q);
        }
    }
    __syncthreads();
    if (tid < 128) {
        const float rs = ls_row[tid];
        const int rowg = tileM * 128 + tid;
        atomicAdd(&total[rowg], rs);
        if (diag) atomicAdd(&selfp[rowg], rs);
    } else if (diag) {
        const int t2 = tid - 128;
        atomicAdd(&ap[tileN * 128 + t2], ls_col[t2]);
    }
}

__global__ __launch_bounds__(256) void infonce_finalize(
    const float* __restrict__ total, const float* __restrict__ selfp,
    const float* __restrict__ ap, float* __restrict__ out)
{
    __shared__ float red[4];
    const int tid = threadIdx.x;
    float s = 0.f;
    for (int e = tid; e < 2048; e += 256) {
        const float an = total[e] - selfp[e];
        s += logf(an / ap[e]);
    }
    #pragma unroll
    for (int m = 32; m >= 1; m >>= 1) s += __shfl_xor(s, m);
    if ((tid & 63) == 0) red[tid >> 6] = s;
    __syncthreads();
    if (tid == 0) out[0] = (red[0] + red[1] + red[2] + red[3]) * (1.0f / 256.0f);
}

extern "C" void kernel_launch(void* const* d_in, const int* in_sizes, int n_in,
                              void* d_out, int out_size, void* d_ws, size_t ws_size,
                              hipStream_t stream) {
    const float* feat     = (const float*)d_in[0];
    const float* feat_aug = (const float*)d_in[1];
    float* total = (float*)d_ws;
    float* selfp = total + 2048;
    float* ap    = selfp + 2048;

    const size_t packBytes = (size_t)2048 * 8192;                  // per tensor, fp8
    const size_t need = 32768 + 2 * packBytes;
    if (ws_size >= need) {
        unsigned char* pA = (unsigned char*)d_ws + 32768;
        unsigned char* pB = pA + packBytes;
        infonce_repack_fp8<<<dim3(2048, 2), 256, 0, stream>>>(feat, feat_aug, pA, pB, total);
        infonce_main_nl<<<dim3(16, 32), 256, 0, stream>>>(pA, pB, total, selfp, ap);
    } else {
        (void)hipMemsetAsync(d_ws, 0, 3 * 2048 * sizeof(float), stream);
        infonce_main_slow<<<dim3(256, 32), 256, 0, stream>>>(feat, feat_aug, total, selfp, ap);
    }
    infonce_finalize<<<1, 256, 0, stream>>>(total, selfp, ap, (float*)d_out);
}